// Round 12
// baseline (145.027 us; speedup 1.0000x reference)
//
#include <hip/hip_runtime.h>
#include <hip/hip_bf16.h>

constexpr int B_ = 4, N_ = 2048, NFEAT = 512, NHID = 64, NHEADS = 4, NCLASS = 64;
constexpr int MAXDEG = 128;
#define LRELU_ALPHA 0.2f

typedef __attribute__((ext_vector_type(8))) short short8;
typedef __attribute__((ext_vector_type(4))) float f32x4;

__device__ __forceinline__ unsigned short f2bf_rne(float f) {
  unsigned int u = __float_as_uint(f);
  unsigned int r = (u + 0x7FFFu + ((u >> 16) & 1u)) >> 16;
  return (unsigned short)r;
}
__device__ __forceinline__ float bf2f(unsigned short h) {
  return __uint_as_float(((unsigned int)h) << 16);
}
__device__ __forceinline__ float ldval(const float* p) { return *p; }
__device__ __forceinline__ float ldval(const unsigned short* p) { return bf2f(*p); }

// ---------------------------------------------------------------------------
// prep_kernel: fused [adjacency-list build | W1 transpose-split | W2 t-split].
// Block ranges: [0,2048) adj rows; [2048,2080) W1 tiles; [2080,2084) W2 tiles.
// ---------------------------------------------------------------------------
__global__ __launch_bounds__(256) void prep_kernel(
    const float* __restrict__ adj, int* __restrict__ nbr, int* __restrict__ deg,
    const float* __restrict__ W1, unsigned short* __restrict__ wt1h,
    unsigned short* __restrict__ wt1l, const float* __restrict__ W2,
    unsigned short* __restrict__ wt2h, unsigned short* __restrict__ wt2l) {
  __shared__ float ts[64][65];
  __shared__ int cnt;
  int bid = blockIdx.x;
  int tid = threadIdx.x;
  if (bid < N_) {
    int n = bid;
    if (tid == 0) cnt = 0;
    __syncthreads();
    for (int m = tid; m < N_; m += 256) {
      bool nz = adj[(size_t)n * N_ + m] != 0.0f;
      unsigned long long mask = __ballot(nz);
      int lane = tid & 63;
      int num = __popcll(mask);
      if (num) {               // wave-uniform
        int base = 0;
        if (lane == 0) base = atomicAdd(&cnt, num);
        base = __shfl(base, 0);
        if (nz) {
          int pos = base + __popcll(mask & ((1ull << lane) - 1ull));
          if (pos < MAXDEG) nbr[n * MAXDEG + pos] = m;
        }
      }
    }
    __syncthreads();
    if (tid == 0) deg[n] = cnt < MAXDEG ? cnt : MAXDEG;
  } else {
    int wk = bid - N_;
    const float* W;
    unsigned short *wth, *wtl;
    int KK, h, k0;
    if (wk < 32) { W = W1; wth = wt1h; wtl = wt1l; KK = 512; h = wk >> 3; k0 = (wk & 7) * 64; }
    else { wk -= 32; W = W2; wth = wt2h; wtl = wt2l; KK = 256; h = 0; k0 = wk * 64; }
    int kr = tid >> 2, nc = (tid & 3) * 16;
    const float* src = W + ((size_t)h * KK + k0 + kr) * 64 + nc;
#pragma unroll
    for (int j = 0; j < 4; ++j)
      *(float4*)&ts[kr][nc + 4 * j] = *(const float4*)(src + 4 * j);
    __syncthreads();
    int n = tid >> 2, kc = (tid & 3) * 16;
    short8 h0, h1v, l0, l1v;
#pragma unroll
    for (int j = 0; j < 8; ++j) {
      float a = ts[kc + j][n];
      float b = ts[kc + 8 + j][n];
      unsigned short ah = f2bf_rne(a), bh = f2bf_rne(b);
      h0[j] = (short)ah; h1v[j] = (short)bh;
      l0[j] = (short)f2bf_rne(a - bf2f(ah));
      l1v[j] = (short)f2bf_rne(b - bf2f(bh));
    }
    size_t o = ((size_t)h * 64 + n) * KK + k0 + kc;
    *(short8*)&wth[o]     = h0;
    *(short8*)&wth[o + 8] = h1v;
    *(short8*)&wtl[o]     = l0;
    *(short8*)&wtl[o + 8] = l1v;
  }
}

// ---------------------------------------------------------------------------
// Split-bf16 MFMA GEMM + fused rowdot epilogue.
// MODE 0 (layer1): X = fp32, split in-kernel; Y -> Yh BF16 [b,n,head*64+d]
//   (h is only ever gather-read by attn1 -> bf16 halves that traffic).
// MODE 1 (layer2): X = pre-split ushort hi/lo; Y -> Yf fp32 [row,64].
// ---------------------------------------------------------------------------
template <int K, int MODE>
__global__ __launch_bounds__(256) void gemm_mfma_kernel(
    const float* __restrict__ Xf, const unsigned short* __restrict__ Xh,
    const unsigned short* __restrict__ Xl, const unsigned short* __restrict__ Wth,
    const unsigned short* __restrict__ Wtl, const float* __restrict__ avec,
    unsigned short* __restrict__ Yh, float* __restrict__ Yf,
    float* __restrict__ so_src, float* __restrict__ so_dst) {
  __shared__ unsigned short xsh[64][72], xsl[64][72], wsh[64][72], wsl[64][72];
  int tid = threadIdx.x;
  int w = tid >> 6, l = tid & 63;
  int row0, head;
  if (MODE == 0) {
    // bid = q*32 + h*8 + x -> rowtile q*8+x, head h (XCD-grouped, kept from R10)
    int bid = blockIdx.x;
    int xcd = bid & 7, hh = (bid >> 3) & 3, q = bid >> 5;
    row0 = (q * 8 + xcd) * 64;
    head = hh;
  } else {
    row0 = blockIdx.x * 64;
    head = 0;
  }
  const unsigned short* wh = Wth + (size_t)head * 64 * K;
  const unsigned short* wl = Wtl + (size_t)head * 64 * K;
  const float* av = avec + head * 128;   // per-head attention vector

  int sr = tid >> 2;            // staging row 0..63
  int sc = (tid & 3) * 16;      // staging col base {0,16,32,48}

  f32x4 acc[4];
#pragma unroll
  for (int nt = 0; nt < 4; ++nt) acc[nt] = (f32x4){0.f, 0.f, 0.f, 0.f};

  for (int k0 = 0; k0 < K; k0 += 64) {
    if (MODE == 0) {
      const float* s0 = Xf + (size_t)(row0 + sr) * K + k0 + sc;
      float4 f0 = ((const float4*)s0)[0];
      float4 f1 = ((const float4*)s0)[1];
      float4 f2 = ((const float4*)s0)[2];
      float4 f3 = ((const float4*)s0)[3];
      float v[16] = {f0.x, f0.y, f0.z, f0.w, f1.x, f1.y, f1.z, f1.w,
                     f2.x, f2.y, f2.z, f2.w, f3.x, f3.y, f3.z, f3.w};
      short8 hi0, hi1, lo0, lo1;
#pragma unroll
      for (int j = 0; j < 8; ++j) {
        unsigned short hh = f2bf_rne(v[j]);
        hi0[j] = (short)hh;
        lo0[j] = (short)f2bf_rne(v[j] - bf2f(hh));
        unsigned short hh1 = f2bf_rne(v[8 + j]);
        hi1[j] = (short)hh1;
        lo1[j] = (short)f2bf_rne(v[8 + j] - bf2f(hh1));
      }
      *(short8*)&xsh[sr][sc]     = hi0;
      *(short8*)&xsh[sr][sc + 8] = hi1;
      *(short8*)&xsl[sr][sc]     = lo0;
      *(short8*)&xsl[sr][sc + 8] = lo1;
    } else {
      const unsigned short* s0 = Xh + (size_t)(row0 + sr) * K + k0 + sc;
      const unsigned short* s1 = Xl + (size_t)(row0 + sr) * K + k0 + sc;
      *(short8*)&xsh[sr][sc]     = *(const short8*)s0;
      *(short8*)&xsh[sr][sc + 8] = *(const short8*)(s0 + 8);
      *(short8*)&xsl[sr][sc]     = *(const short8*)s1;
      *(short8*)&xsl[sr][sc + 8] = *(const short8*)(s1 + 8);
    }
    {
      const unsigned short* s2 = wh + (size_t)sr * K + k0 + sc;
      const unsigned short* s3 = wl + (size_t)sr * K + k0 + sc;
      *(short8*)&wsh[sr][sc]     = *(const short8*)s2;
      *(short8*)&wsh[sr][sc + 8] = *(const short8*)(s2 + 8);
      *(short8*)&wsl[sr][sc]     = *(const short8*)s3;
      *(short8*)&wsl[sr][sc + 8] = *(const short8*)(s3 + 8);
    }
    __syncthreads();
#pragma unroll
    for (int ks = 0; ks < 2; ++ks) {
      int ko = ks * 32 + (l >> 4) * 8;
      int ar = 16 * w + (l & 15);
      short8 ah = *(const short8*)&xsh[ar][ko];
      short8 al = *(const short8*)&xsl[ar][ko];
#pragma unroll
      for (int nt = 0; nt < 4; ++nt) {
        int br = 16 * nt + (l & 15);
        short8 bh = *(const short8*)&wsh[br][ko];
        short8 bl = *(const short8*)&wsl[br][ko];
        acc[nt] = __builtin_amdgcn_mfma_f32_16x16x32_bf16(ah, bh, acc[nt], 0, 0, 0);
        acc[nt] = __builtin_amdgcn_mfma_f32_16x16x32_bf16(ah, bl, acc[nt], 0, 0, 0);
        acc[nt] = __builtin_amdgcn_mfma_f32_16x16x32_bf16(al, bh, acc[nt], 0, 0, 0);
      }
    }
    __syncthreads();
  }

  int col = (l & 15);
#pragma unroll
  for (int nt = 0; nt < 4; ++nt) {
#pragma unroll
    for (int j = 0; j < 4; ++j) {
      int r = 16 * w + (l >> 4) * 4 + j;
      size_t gr = row0 + r;
      if (MODE == 0)
        Yh[gr * (NHEADS * 64) + head * 64 + 16 * nt + col] = f2bf_rne(acc[nt][j]);
      else
        Yf[gr * 64 + 16 * nt + col] = acc[nt][j];
    }
  }
  float aS[4], aD[4];
#pragma unroll
  for (int nt = 0; nt < 4; ++nt) {
    aS[nt] = av[16 * nt + col];
    aD[nt] = av[64 + 16 * nt + col];
  }
  float s1[4] = {0.f, 0.f, 0.f, 0.f}, s2[4] = {0.f, 0.f, 0.f, 0.f};
#pragma unroll
  for (int nt = 0; nt < 4; ++nt)
#pragma unroll
    for (int j = 0; j < 4; ++j) {
      s1[j] = fmaf(acc[nt][j], aS[nt], s1[j]);
      s2[j] = fmaf(acc[nt][j], aD[nt], s2[j]);
    }
#pragma unroll
  for (int off = 1; off < 16; off <<= 1) {
#pragma unroll
    for (int j = 0; j < 4; ++j) {
      s1[j] += __shfl_xor(s1[j], off);
      s2[j] += __shfl_xor(s2[j], off);
    }
  }
  if (col == 0) {
#pragma unroll
    for (int j = 0; j < 4; ++j) {
      int r = 16 * w + (l >> 4) * 4 + j;
      int gr = row0 + r;
      size_t si;
      if (MODE == 0) {
        int b = gr >> 11, n = gr & (N_ - 1);
        si = (size_t)(b * NHEADS + head) * N_ + n;
      } else {
        si = gr;
      }
      so_src[si] = s1[j];
      so_dst[si] = s2[j];
    }
  }
}

// ---------------------------------------------------------------------------
// Sparse attention aggregation: 16-deep then 8-deep software pipeline.
// RS = row stride; T = plane element type (float | bf16-as-ushort).
// ---------------------------------------------------------------------------
template <int RS, typename T>
__device__ __forceinline__ float sparse_agg(
    const T* __restrict__ plane, const float* __restrict__ sdb,
    const int* __restrict__ nb, int dg, float ss, int lane) {
  float acc0 = 0.f, acc1 = 0.f, acc2 = 0.f, acc3 = 0.f;
  float den0 = 0.f, den1 = 0.f, den2 = 0.f, den3 = 0.f;
  int k = 0;
  for (; k + 16 <= dg; k += 16) {
    int m[16];
    float sv[16], hv[16];
#pragma unroll
    for (int j = 0; j < 16; ++j) m[j] = nb[k + j];
#pragma unroll
    for (int j = 0; j < 16; ++j) sv[j] = sdb[m[j]];
#pragma unroll
    for (int j = 0; j < 16; ++j) hv[j] = ldval(&plane[(size_t)m[j] * RS + lane]);
#pragma unroll
    for (int j = 0; j < 16; ++j) {
      float s = ss + sv[j];
      float lr = s > 0.f ? s : LRELU_ALPHA * s;
      float ev = __expf(-lr);
      switch (j & 3) {
        case 0: den0 += ev; acc0 = fmaf(ev, hv[j], acc0); break;
        case 1: den1 += ev; acc1 = fmaf(ev, hv[j], acc1); break;
        case 2: den2 += ev; acc2 = fmaf(ev, hv[j], acc2); break;
        default: den3 += ev; acc3 = fmaf(ev, hv[j], acc3); break;
      }
    }
  }
  for (; k + 8 <= dg; k += 8) {
    int m[8];
    float sv[8], hv[8];
#pragma unroll
    for (int j = 0; j < 8; ++j) m[j] = nb[k + j];
#pragma unroll
    for (int j = 0; j < 8; ++j) sv[j] = sdb[m[j]];
#pragma unroll
    for (int j = 0; j < 8; ++j) hv[j] = ldval(&plane[(size_t)m[j] * RS + lane]);
#pragma unroll
    for (int j = 0; j < 8; ++j) {
      float s = ss + sv[j];
      float lr = s > 0.f ? s : LRELU_ALPHA * s;
      float ev = __expf(-lr);
      if (j & 1) { den1 += ev; acc1 = fmaf(ev, hv[j], acc1); }
      else       { den0 += ev; acc0 = fmaf(ev, hv[j], acc0); }
    }
  }
  for (; k < dg; ++k) {
    int m = nb[k];
    float s = ss + sdb[m];
    float lr = s > 0.f ? s : LRELU_ALPHA * s;
    float ev = __expf(-lr);
    den0 += ev;
    acc0 = fmaf(ev, ldval(&plane[(size_t)m * RS + lane]), acc0);
  }
  return ((acc0 + acc1) + (acc2 + acc3)) / ((den0 + den1) + (den2 + den3));
}

// ---------------------------------------------------------------------------
// Layer-1 aggregation: one BLOCK per (b,n); 4 waves = 4 heads. h is BF16.
// ---------------------------------------------------------------------------
__global__ __launch_bounds__(256) void attn1_kernel(
    const unsigned short* __restrict__ Hm, const float* __restrict__ ssrc,
    const float* __restrict__ sdst, const int* __restrict__ nbr,
    const int* __restrict__ deg, unsigned short* __restrict__ h1h,
    unsigned short* __restrict__ h1l) {
  int bn = blockIdx.x;               // 0..B*N-1
  int n = bn & (N_ - 1), b = bn >> 11;
  int w = threadIdx.x >> 6;          // head
  int lane = threadIdx.x & 63;
  __shared__ int lds_nbr[MAXDEG];
  int dg = deg[n];
  for (int k = threadIdx.x; k < dg; k += 256) lds_nbr[k] = nbr[n * MAXDEG + k];
  __syncthreads();
  int bh = b * NHEADS + w;
  float ss = ssrc[(size_t)bh * N_ + n];
  const float* sdb = sdst + (size_t)bh * N_;
  const unsigned short* plane = Hm + (size_t)b * N_ * (NHEADS * 64) + w * 64;
  float o = sparse_agg<NHEADS * 64>(plane, sdb, lds_nbr, dg, ss, lane);
  o = o > 0.f ? o : expm1f(o);
  unsigned short hi = f2bf_rne(o);
  size_t oi = (size_t)bn * (NHEADS * NHID) + w * 64 + lane;
  h1h[oi] = hi;
  h1l[oi] = f2bf_rne(o - bf2f(hi));
}

// ---------------------------------------------------------------------------
// Layer-2 aggregation + final ELU -> d_out. One wave per (b,n). g stays fp32.
// ---------------------------------------------------------------------------
__global__ __launch_bounds__(256) void attn2_kernel(
    const float* __restrict__ G, const float* __restrict__ tsrc,
    const float* __restrict__ tdst, const int* __restrict__ nbr,
    const int* __restrict__ deg, float* __restrict__ out) {
  int w = threadIdx.x >> 6, lane = threadIdx.x & 63;
  int gr = blockIdx.x * 4 + w;        // 0..B*N
  int n = gr & (N_ - 1);
  int b = gr >> 11;
  float o = sparse_agg<64>(G + (size_t)b * N_ * 64, tdst + (size_t)b * N_,
                           nbr + n * MAXDEG, deg[n], tsrc[gr], lane);
  out[(size_t)gr * 64 + lane] = o > 0.f ? o : expm1f(o);
}

// ---------------------------------------------------------------------------
extern "C" void kernel_launch(void* const* d_in, const int* in_sizes, int n_in,
                              void* d_out, int out_size, void* d_ws, size_t ws_size,
                              hipStream_t stream) {
  const float* x   = (const float*)d_in[0];   // [B,N,512]
  const float* adj = (const float*)d_in[1];   // [N,N]
  const float* W1  = (const float*)d_in[2];   // [H,512,64]
  const float* a1  = (const float*)d_in[3];   // [H,128]
  const float* W2  = (const float*)d_in[4];   // [256,64]
  const float* a2  = (const float*)d_in[5];   // [128]
  float* out = (float*)d_out;                 // [B,N,64] fp32

  char* ws = (char*)d_ws;
  unsigned short* h = (unsigned short*)ws; ws += (size_t)B_ * N_ * 256 * 2;  // 4.2 MB bf16
  float* g    = (float*)ws; ws += (size_t)B_ * N_ * 64 * 4;           // 2 MB
  float* ssrc = (float*)ws; ws += (size_t)B_ * NHEADS * N_ * 4;
  float* sdst = (float*)ws; ws += (size_t)B_ * NHEADS * N_ * 4;
  float* tsrc = (float*)ws; ws += (size_t)B_ * N_ * 4;
  float* tdst = (float*)ws; ws += (size_t)B_ * N_ * 4;
  int*   nbr  = (int*)ws;   ws += (size_t)N_ * MAXDEG * 4;            // 1 MB
  int*   deg  = (int*)ws;   ws += (size_t)N_ * 4;
  ws = (char*)(((size_t)ws + 255) & ~(size_t)255);
  unsigned short* wt1h = (unsigned short*)ws; ws += (size_t)NHEADS * 64 * NFEAT * 2;
  unsigned short* wt1l = (unsigned short*)ws; ws += (size_t)NHEADS * 64 * NFEAT * 2;
  unsigned short* wt2h = (unsigned short*)ws; ws += (size_t)64 * 256 * 2;
  unsigned short* wt2l = (unsigned short*)ws; ws += (size_t)64 * 256 * 2;
  unsigned short* h1h  = (unsigned short*)ws; ws += (size_t)B_ * N_ * 256 * 2;   // 4.2 MB
  unsigned short* h1l  = (unsigned short*)ws; ws += (size_t)B_ * N_ * 256 * 2;   // 4.2 MB

  // prep: blocks [0,2048) adj | [2048,2080) W1 | [2080,2084) W2
  prep_kernel<<<N_ + 32 + 4, 256, 0, stream>>>(adj, nbr, deg, W1, wt1h, wt1l,
                                               W2, wt2h, wt2l);
  gemm_mfma_kernel<NFEAT, 0><<<B_ * N_ / 64 * NHEADS, 256, 0, stream>>>(
      x, nullptr, nullptr, wt1h, wt1l, a1, h, nullptr, ssrc, sdst);
  attn1_kernel<<<B_ * N_, 256, 0, stream>>>(h, ssrc, sdst, nbr, deg, h1h, h1l);
  gemm_mfma_kernel<256, 1><<<B_ * N_ / 64, 256, 0, stream>>>(
      nullptr, h1h, h1l, wt2h, wt2l, a2, nullptr, g, tsrc, tdst);
  attn2_kernel<<<B_ * N_ / 4, 256, 0, stream>>>(g, tsrc, tdst, nbr, deg, out);
}